// Round 9
// baseline (1297.546 us; speedup 1.0000x reference)
//
#include <hip/hip_runtime.h>
#include <stdint.h>

// RandomPropagate: 100 steps of jitter -> 3x3 maxpool -> coin mask -> goodness
// scale -> threshold commit, on a 2048x2048 f32 grid.
//
// Round 9 = Round 8 (row-bitmask passes, verified absmax 0.0) +
//  - per-tile buffer indirection: status byte bit0=active, bit1=cur buffer
//    (0=A=d_out, 1=B=d_ws). Tiles with no commits this launch write NOTHING
//    (keep bit); committing tiles write central to !cur and toggle. Staging
//    reads each 3x3 neighbor region from that neighbor's cur buffer (LDS
//    pointer table; every pixel owned by exactly one tile => readers read
//    cur, writers write !cur, statuses ping-pong => race-free). Final
//    k_gather copies cur==B tiles into d_out. Kills the 16.4 MB/launch
//    full-grid ping-pong copy (uniform WRITE_SIZE seen in R8 counters).
//  - nz-row gating of the s=0 flag pass: a row can only flag if its 3-row
//    window has a value > 0.05 (fl(M-x) <= M <= 0.05 otherwise, fl monotone);
//    staging ballots (x > 0.05) per row; s=0 iterates dilate1(nzrows) only.
// Core automaton machinery unchanged from R8 (ub flags, incremental re-eval,
// frontier-gated jitter, exact-test-gated coin). Every consumed RNG bit and
// f32 rounding on consumed paths identical to the reference.
//
// PRNG: JAX threefry2x32, partitionable mode (bit-exact, absmax 0.0 R1-R8):
//   fold_in(key, i)       = tf2x32(key, (0, i))
//   split(F)[j]           = tf2x32(F,   (0, j))
//   random_bits32(key, p) = o0 ^ o1 of tf2x32(key, (0, p))
//   uniform01(bits)       = bitcast((bits>>9)|0x3f800000) - 1.0f
// All f32 math uses _rn intrinsics to forbid FMA contraction.

#define HH 2048
#define WW 2048
#define NPIX (HH * WW)
#define SD 64           // staged tile side (1 wave per row)
#define OT 32           // output tile side
#define HALO 16
#define K_MAX 16
#define NB (WW / OT)    // 64 tile-blocks per side
#define NTILE (NB * NB)

// ---------- threefry2x32, exact JAX round structure ----------
__host__ __device__ __forceinline__ void tf2x32(uint32_t k0, uint32_t k1,
                                                uint32_t c0, uint32_t c1,
                                                uint32_t* o0, uint32_t* o1) {
  uint32_t ks2 = k0 ^ k1 ^ 0x1BD11BDAu;
  uint32_t x0 = c0 + k0, x1 = c1 + k1;
#define TFR(r) do { x0 += x1; x1 = (x1 << (r)) | (x1 >> (32 - (r))); x1 ^= x0; } while (0);
  TFR(13) TFR(15) TFR(26) TFR(6)
  x0 += k1; x1 += ks2 + 1u;
  TFR(17) TFR(29) TFR(16) TFR(24)
  x0 += ks2; x1 += k0 + 2u;
  TFR(13) TFR(15) TFR(26) TFR(6)
  x0 += k0; x1 += k1 + 3u;
  TFR(17) TFR(29) TFR(16) TFR(24)
  x0 += k1; x1 += ks2 + 4u;
  TFR(13) TFR(15) TFR(26) TFR(6)
  x0 += ks2; x1 += k0 + 5u;
#undef TFR
  *o0 = x0; *o1 = x1;
}

__device__ __forceinline__ float uniform01(uint32_t ka, uint32_t kb, uint32_t p) {
  uint32_t o0, o1;
  tf2x32(ka, kb, 0u, p, &o0, &o1);
  uint32_t bits = o0 ^ o1;  // partitionable 32-bit XOR fold
  return __uint_as_float((bits >> 9) | 0x3F800000u) - 1.0f;
}

__device__ __forceinline__ unsigned long long dil1(unsigned long long m) {
  return m | (m << 1) | (m >> 1);
}
__device__ __forceinline__ unsigned long long rmask(int lo, int hi) {
  return (~0ULL >> (63 - (hi - lo))) << lo;  // bits lo..hi
}

struct Keys {
  uint32_t a0[K_MAX], a1[K_MAX], b0[K_MAX], b1[K_MAX];
  int K;
};

// x0 = seed*habitat*goodness (seed exactly 0/1 => rounding exact); arm
// statuses: all tiles active, cur = B.
__global__ void k_init(const float* __restrict__ seed,
                       const float* __restrict__ hab,
                       const float* __restrict__ good,
                       float* __restrict__ x,
                       unsigned char* __restrict__ st) {
  int p = blockIdx.x * blockDim.x + threadIdx.x;
  if (p >= NPIX) return;
  x[p] = __fmul_rn(__fmul_rn(seed[p], hab[p]), good[p]);
  if (p < NTILE) st[p] = 3;  // active | cur=B
}

// consolidate: tiles whose current buffer is B copy their central into A
__global__ void k_gather(const float* __restrict__ src,
                         float* __restrict__ dst,
                         const unsigned char* __restrict__ st) {
  int tix = blockIdx.x;
  if (!(st[tix] & 2)) return;  // already in A (written this call)
  int by = tix >> 6, bx = tix & (NB - 1);
  int r = threadIdx.x >> 3, c4 = threadIdx.x & 7;
  int off = (by * OT + r) * WW + bx * OT + 4 * c4;
  *(float4*)(dst + off) = *(const float4*)(src + off);
}

__global__ __launch_bounds__(256) void k_fused(float* __restrict__ bufA,
                                               float* __restrict__ bufB,
                                               const float* __restrict__ good,
                                               const unsigned char* __restrict__ st_in,
                                               unsigned char* __restrict__ st_out,
                                               Keys kk) {
  __shared__ float xs[SD * SD];                // current x
  __shared__ float ts[SD * SD];                // jittered field (frontier only)
  __shared__ unsigned long long fm[SD];        // per-row flag mask
  __shared__ unsigned long long cm[SD];        // commit masks (crw-guarded)
  __shared__ unsigned int s_flr[2];            // flagrows bitmask
  __shared__ unsigned int s_crw[2];            // commitrows bitmask
  __shared__ unsigned int s_nzr[2];            // rows with any x > 0.05
  __shared__ const float* s_ptr[9];            // per-neighbor cur buffer
  __shared__ int s_skip, s_mystat, s_committed;

  const int tid = threadIdx.x;
  const int wv = tid >> 6, ln = tid & 63;      // wave id (0..3), lane (=col)
  const int bx = blockIdx.x, by = blockIdx.y;
  const int tix = by * NB + bx;
  const int r0b = by * OT, c0b = bx * OT;      // output origin
  const int r0g = r0b - HALO, c0g = c0b - HALO;  // staged origin
  const bool top = (by == 0), bot = (by == NB - 1);
  const bool lef = (bx == 0), rig = (bx == NB - 1);
  const bool edge = top || bot || lef || rig;

  // ---- neighbor status scan: activity + buffer pointers
  {
    bool act = false;
    if (tid < 9) {
      int dy = tid / 3 - 1, dx = tid % 3 - 1;
      int ny = by + dy, nx = bx + dx;
      unsigned char stv = 0;
      if (ny >= 0 && ny < NB && nx >= 0 && nx < NB) stv = st_in[ny * NB + nx];
      act = (stv & 1) != 0;
      s_ptr[tid] = (stv & 2) ? bufB : bufA;
      if (tid == 4) s_mystat = stv;
    }
    unsigned long long b = __ballot(act);      // meaningful in wave 0
    if (tid == 0) s_skip = (b == 0ULL);
    if (tid < 2) { s_flr[tid] = 0u; s_crw[tid] = 0u; s_nzr[tid] = 0u; }
    if (tid == 0) s_committed = 0;
    __syncthreads();
  }
  const int mycur = (s_mystat >> 1) & 1;
  if (s_skip) {  // whole 3x3 quiet: frozen, data stays where it is
    if (tid == 0) st_out[tix] = (unsigned char)(mycur << 1);
    return;
  }

  // ---- stage raw x from per-tile cur buffers (clamp == -inf pad for max);
  //      also build nz-row mask (any x > 0.05 in row)
  if (!edge) {
#pragma unroll
    for (int k = 0; k < 4; ++k) {
      int q = tid + 256 * k;                   // 1024 float4s
      int sr = q >> 4, c4 = q & 15;
      int gr = r0g + sr, gc = c0g + 4 * c4;
      const float* base = s_ptr[((gr >> 5) - (by - 1)) * 3 + ((gc >> 5) - (bx - 1))];
      float4 v = *(const float4*)(base + gr * WW + gc);
      ((float4*)xs)[q] = v;
      bool any = v.x > 0.05f || v.y > 0.05f || v.z > 0.05f || v.w > 0.05f;
      unsigned long long b = __ballot(any);    // 4 rows x 16 lanes per wave
      if (ln == 0) {
        int rr = 4 * wv + 16 * k;              // 4-aligned: no word straddle
        unsigned int mb = 0;
#pragma unroll
        for (int i = 0; i < 4; ++i)
          if ((b >> (16 * i)) & 0xFFFFULL) mb |= 1u << i;
        if (mb) atomicOr(&s_nzr[rr >> 5], mb << (rr & 31));
      }
    }
  } else {
    for (int k = 0; k < 16; ++k) {
      int idx = tid + 256 * k;                 // one row per wave per iter
      int sr = idx >> 6, sc = idx & 63;
      int gr = r0g + sr; gr = gr < 0 ? 0 : (gr > HH - 1 ? HH - 1 : gr);
      int gc = c0g + sc; gc = gc < 0 ? 0 : (gc > WW - 1 ? WW - 1 : gc);
      const float* base = s_ptr[((gr >> 5) - (by - 1)) * 3 + ((gc >> 5) - (bx - 1))];
      float xv = base[gr * WW + gc];
      xs[idx] = xv;
      unsigned long long b = __ballot(xv > 0.05f);
      if (ln == 0 && b) atomicOr(&s_nzr[sr >> 5], 1u << (sr & 31));
    }
  }
  if (tid < SD) fm[tid] = 0ULL;
  __syncthreads();

  int broke = 0;
  for (int s = 0; s < kk.K; ++s) {
    // exactly-updatable rect this step (local coords)
    const int rlo = top ? HALO : s + 1;
    const int rhi = bot ? HALO + OT - 1 : SD - 2 - s;
    const int clo = lef ? HALO : s + 1;
    const int chi = rig ? HALO + OT - 1 : SD - 2 - s;
    const unsigned long long colw = rmask(clo, chi);
    const unsigned long long rowsrect = rmask(rlo, rhi);
    const unsigned long long crw_prev =
        s_crw[0] | ((unsigned long long)s_crw[1] << 32);

    // ---- pass A: flag eval (nz-gated full eval at s=0; commit-driven after)
    if (s == 0) {
      unsigned long long nzr = s_nzr[0] | ((unsigned long long)s_nzr[1] << 32);
      unsigned long long arows = dil1(nzr) & rowsrect;
      int idx = 0;
      while (arows) {
        int r = __builtin_ctzll(arows); arows &= arows - 1;
        if (((idx++) & 3) != wv) continue;
        float a = xs[((r - 1) << 6) + ln];
        float b = xs[(r << 6) + ln];
        float c = xs[((r + 1) << 6) + ln];
        float vv = fmaxf(fmaxf(a, b), c);      // vertical max, own col
        float hl = __shfl(vv, ln - 1);         // junk at lane 0 (never valid)
        float hr = __shfl(vv, ln + 1);         // junk at lane 63 (never valid)
        float M = fmaxf(fmaxf(hl, vv), hr);
        bool flag = false;
        if ((colw >> ln) & 1ULL) {
          float xv = b;
          if (__fsub_rn(M, xv) > 0.05f) {      // pre-test: good<1 => ub <= M
            float g = good[(r0g + r) * WW + (c0g + ln)];
            if (__fsub_rn(__fmul_rn(M, g), xv) > 0.05f) flag = true;
          }
        }
        unsigned long long f = __ballot(flag) & colw;
        if (ln == 0) {
          fm[r] = f;
          if (f) atomicOr(&s_flr[r >> 5], 1u << (r & 31));
        }
      }
      // rows outside dil1(nzr): window max <= 0.05 => fl(M-x) <= 0.05, no flag
    } else {
      unsigned long long arows = dil1(crw_prev) & rowsrect;
      int idx = 0;
      while (arows) {
        int r = __builtin_ctzll(arows); arows &= arows - 1;
        if (((idx++) & 3) != wv) continue;
        unsigned long long cn = 0ULL;
        if ((crw_prev >> (r - 1)) & 1ULL) cn |= cm[r - 1];
        if ((crw_prev >> r) & 1ULL) cn |= cm[r];
        if ((crw_prev >> (r + 1)) & 1ULL) cn |= cm[r + 1];
        unsigned long long d = dil1(cn) & colw;
        if (!d) continue;
        float a = xs[((r - 1) << 6) + ln];
        float b = xs[(r << 6) + ln];
        float c = xs[((r + 1) << 6) + ln];
        float vv = fmaxf(fmaxf(a, b), c);
        float hl = __shfl(vv, ln - 1);
        float hr = __shfl(vv, ln + 1);
        float M = fmaxf(fmaxf(hl, vv), hr);
        bool flag = false;
        if ((d >> ln) & 1ULL) {
          float xv = b;
          if (__fsub_rn(M, xv) > 0.05f) {
            float g = good[(r0g + r) * WW + (c0g + ln)];
            if (__fsub_rn(__fmul_rn(M, g), xv) > 0.05f) flag = true;
          }
        }
        unsigned long long f = (fm[r] & ~d) | (__ballot(flag) & d);
        if (ln == 0) {
          fm[r] = f;
          if (f) atomicOr(&s_flr[r >> 5], 1u << (r & 31));
          else   atomicAnd(&s_flr[r >> 5], ~(1u << (r & 31)));
        }
      }
    }
    __syncthreads();  // B1: fm/flagrows visible

    const unsigned long long flr =
        s_flr[0] | ((unsigned long long)s_flr[1] << 32);
    if (!(flr & rowsrect)) { broke = 1; break; }  // frozen => forever

    // ---- jitter frontier (rows in dilate1(flagrows)); clear commitrows
    if (tid < 2) s_crw[tid] = 0u;
    {
      unsigned long long jrows = dil1(flr) & rmask(rlo - 1, rhi + 1);
      int idx = 0;
      while (jrows) {
        int r = __builtin_ctzll(jrows); jrows &= jrows - 1;
        if (((idx++) & 3) != wv) continue;
        unsigned long long fu = 0ULL;
        if (r - 1 >= rlo && r - 1 <= rhi) fu |= fm[r - 1];
        if (r     >= rlo && r     <= rhi) fu |= fm[r];
        if (r + 1 >= rlo && r + 1 <= rhi) fu |= fm[r + 1];
        fu &= colw;
        if (!fu) continue;
        unsigned long long need = dil1(fu);
        if ((need >> ln) & 1ULL) {
          float xv = xs[(r << 6) + ln];
          float tv = 0.0f;
          if (xv != 0.0f) {                    // t = 0*s1 == +0 exactly
            int gr = r0g + r;  gr = gr < 0 ? 0 : (gr > HH - 1 ? HH - 1 : gr);
            int gc = c0g + ln; gc = gc < 0 ? 0 : (gc > WW - 1 ? WW - 1 : gc);
            float u = uniform01(kk.a0[s], kk.a1[s], (uint32_t)(gr * WW + gc));
            float s1 = __fadd_rn((float)(1.0 - 1e-4), __fmul_rn(1e-4f, u));
            tv = __fmul_rn(xv, s1);
          }
          ts[(r << 6) + ln] = tv;
        }
      }
    }
    __syncthreads();  // B2: ts visible, crw cleared

    // ---- pass B: exact maxpool(t) + coin + commit at flagged px
    {
      unsigned long long brows = flr & rowsrect;
      int idx = 0;
      while (brows) {
        int r = __builtin_ctzll(brows); brows &= brows - 1;
        if (((idx++) & 3) != wv) continue;
        unsigned long long wf = fm[r] & colw;
        if (!wf) continue;
        // ts garbage only exists >1 lane away from any flag, never consumed
        float t0 = ts[((r - 1) << 6) + ln];
        float t1 = ts[(r << 6) + ln];
        float t2 = ts[((r + 1) << 6) + ln];
        float vt = fmaxf(fmaxf(t0, t1), t2);
        float hl = __shfl(vt, ln - 1);
        float hr = __shfl(vt, ln + 1);
        float m = fmaxf(fmaxf(hl, vt), hr);
        bool ok = false;
        float v = 0.0f;
        if ((wf >> ln) & 1ULL) {
          int gp = (r0g + r) * WW + (c0g + ln);  // in rect => in bounds
          float xv = xs[(r << 6) + ln];
          v = __fmul_rn(m, good[gp]);
          if (__fsub_rn(v, xv) > 0.05f) {      // exact test -> coin draw
            float u2 = uniform01(kk.b0[s], kk.b1[s], (uint32_t)gp);
            ok = (u2 > 0.5f);
          }
        }
        unsigned long long bal = __ballot(ok);
        if (ok) xs[(r << 6) + ln] = v;         // max(v,x)=v since v-x>THR>0
        if (bal && ln == 0) {
          cm[r] = bal;
          atomicOr(&s_crw[r >> 5], 1u << (r & 31));
          s_committed = 1;
        }
      }
    }
    __syncthreads();  // B3: commits/crw/s_committed visible

    // ---- refresh dup ring for grid-edge tiles (only layer 15/48 is read)
    if (edge) {
      unsigned long long crw =
          s_crw[0] | ((unsigned long long)s_crw[1] << 32);
      if (crw) {  // no commits => xs unchanged => ring still valid
        if (top && tid < SD) xs[(15 << 6) + tid] = xs[(16 << 6) + tid];
        if (bot && tid < SD) xs[(48 << 6) + tid] = xs[(47 << 6) + tid];
        __syncthreads();
        if (lef && tid < SD) xs[(tid << 6) + 15] = xs[(tid << 6) + 16];
        if (rig && tid < SD) xs[(tid << 6) + 48] = xs[(tid << 6) + 47];
        __syncthreads();
      }
    }
  }

  // ---- writeback only if something changed; toggle cur bit accordingly
  int newcur = mycur;
  if (s_committed) {  // set-before-B3 of its step => visible (exits barrier'd)
    newcur = mycur ^ 1;
    float* dst = mycur ? bufA : bufB;          // write the OTHER buffer
    int r = tid >> 3, c4 = tid & 7;            // 32 rows x 8 float4
    *(float4*)(dst + (r0b + r) * WW + c0b + 4 * c4) =
        *(const float4*)(xs + ((r + HALO) << 6) + HALO + 4 * c4);
  }
  if (tid == 0)
    st_out[tix] = (unsigned char)((broke ? 0 : 1) | (newcur << 1));
}

extern "C" void kernel_launch(void* const* d_in, const int* in_sizes, int n_in,
                              void* d_out, int out_size, void* d_ws, size_t ws_size,
                              hipStream_t stream) {
  const float* seed = (const float*)d_in[0];
  const float* hab  = (const float*)d_in[1];
  const float* good = (const float*)d_in[2];
  float* bufA = (float*)d_out;
  float* bufB = (float*)d_ws;
  unsigned char* stA = (unsigned char*)d_ws + (16u << 20);  // after bufB
  unsigned char* stB = stA + NTILE;

  k_init<<<dim3(NPIX / 256), dim3(256), 0, stream>>>(seed, hab, good, bufB, stA);

  // sum(delta)==0.0 exactly (required for early exit) is unreachable once any
  // seed is nonzero (coin toss gives delta = -x < 0 somewhere) -> all 100 steps.
  unsigned char* stIn = stA; unsigned char* stOut = stB;
  dim3 grd(NB, NB), blk(256);
  for (int base = 0; base < 100; base += K_MAX) {
    Keys kk;
    kk.K = (100 - base < K_MAX) ? (100 - base) : K_MAX;
    for (int s = 0; s < kk.K; ++s) {
      uint32_t f0, f1;
      tf2x32(0u, 42u, 0u, (uint32_t)(base + s), &f0, &f1);  // fold_in(key, i)
      tf2x32(f0, f1, 0u, 0u, &kk.a0[s], &kk.a1[s]);         // split -> jitter
      tf2x32(f0, f1, 0u, 1u, &kk.b0[s], &kk.b1[s]);         // split -> coin
    }
    k_fused<<<grd, blk, 0, stream>>>(bufA, bufB, good, stIn, stOut, kk);
    unsigned char* t = stIn; stIn = stOut; stOut = t;
  }
  // consolidate: tiles whose final cur buffer is B -> copy central into d_out
  k_gather<<<dim3(NTILE), blk, 0, stream>>>(bufB, bufA, stIn);
}

// Round 10
// 1230.335 us; speedup vs baseline: 1.0546x; 1.0546x over previous
//
#include <hip/hip_runtime.h>
#include <stdint.h>

// RandomPropagate: 100 steps of jitter -> 3x3 maxpool -> coin mask -> goodness
// scale -> threshold commit, on a 2048x2048 f32 grid.
//
// Round 10 = Round 9 (per-tile buffer indirection + nz-row gating, verified
// absmax 0.0) + flag-staleness fix. R9 counters showed FETCH ~30 MB uniform
// across ALL launches => tiles never broke. Cause: fm[r] kept columns that
// left the shrinking rect (colw); they were masked at consumption but not in
// the flr row-bitmask, so flr&rowsrect never cleared, tiles stayed active
// forever and poisoned the 9-tile skip rule. Fixes (consumed values 100%
// unchanged -- out-of-colw flags could never commit anyway):
//  1. pass A stores fm[r] &= colw (colw only shrinks => dropping is final).
//  2. pass B clears the flr row bit when fm[r]&colw==0 (self-cleaning; pass A
//     re-arms via commits).
//  3. jitter rows = dilate1(flr & rowsrect) (still covers all pass-B reads).
// Everything else identical to R9: ub flags (monotone bound), incremental
// re-eval, frontier-gated jitter, exact-test-gated coin, per-tile cur-buffer
// indirection, cross-launch 9-neighborhood skip.
//
// PRNG: JAX threefry2x32, partitionable mode (bit-exact, absmax 0.0 R1-R9):
//   fold_in(key, i)       = tf2x32(key, (0, i))
//   split(F)[j]           = tf2x32(F,   (0, j))
//   random_bits32(key, p) = o0 ^ o1 of tf2x32(key, (0, p))
//   uniform01(bits)       = bitcast((bits>>9)|0x3f800000) - 1.0f
// All f32 math uses _rn intrinsics to forbid FMA contraction.

#define HH 2048
#define WW 2048
#define NPIX (HH * WW)
#define SD 64           // staged tile side (1 wave per row)
#define OT 32           // output tile side
#define HALO 16
#define K_MAX 16
#define NB (WW / OT)    // 64 tile-blocks per side
#define NTILE (NB * NB)

// ---------- threefry2x32, exact JAX round structure ----------
__host__ __device__ __forceinline__ void tf2x32(uint32_t k0, uint32_t k1,
                                                uint32_t c0, uint32_t c1,
                                                uint32_t* o0, uint32_t* o1) {
  uint32_t ks2 = k0 ^ k1 ^ 0x1BD11BDAu;
  uint32_t x0 = c0 + k0, x1 = c1 + k1;
#define TFR(r) do { x0 += x1; x1 = (x1 << (r)) | (x1 >> (32 - (r))); x1 ^= x0; } while (0);
  TFR(13) TFR(15) TFR(26) TFR(6)
  x0 += k1; x1 += ks2 + 1u;
  TFR(17) TFR(29) TFR(16) TFR(24)
  x0 += ks2; x1 += k0 + 2u;
  TFR(13) TFR(15) TFR(26) TFR(6)
  x0 += k0; x1 += k1 + 3u;
  TFR(17) TFR(29) TFR(16) TFR(24)
  x0 += k1; x1 += ks2 + 4u;
  TFR(13) TFR(15) TFR(26) TFR(6)
  x0 += ks2; x1 += k0 + 5u;
#undef TFR
  *o0 = x0; *o1 = x1;
}

__device__ __forceinline__ float uniform01(uint32_t ka, uint32_t kb, uint32_t p) {
  uint32_t o0, o1;
  tf2x32(ka, kb, 0u, p, &o0, &o1);
  uint32_t bits = o0 ^ o1;  // partitionable 32-bit XOR fold
  return __uint_as_float((bits >> 9) | 0x3F800000u) - 1.0f;
}

__device__ __forceinline__ unsigned long long dil1(unsigned long long m) {
  return m | (m << 1) | (m >> 1);
}
__device__ __forceinline__ unsigned long long rmask(int lo, int hi) {
  return (~0ULL >> (63 - (hi - lo))) << lo;  // bits lo..hi
}

struct Keys {
  uint32_t a0[K_MAX], a1[K_MAX], b0[K_MAX], b1[K_MAX];
  int K;
};

// x0 = seed*habitat*goodness (seed exactly 0/1 => rounding exact); arm
// statuses: all tiles active, cur = B.
__global__ void k_init(const float* __restrict__ seed,
                       const float* __restrict__ hab,
                       const float* __restrict__ good,
                       float* __restrict__ x,
                       unsigned char* __restrict__ st) {
  int p = blockIdx.x * blockDim.x + threadIdx.x;
  if (p >= NPIX) return;
  x[p] = __fmul_rn(__fmul_rn(seed[p], hab[p]), good[p]);
  if (p < NTILE) st[p] = 3;  // active | cur=B
}

// consolidate: tiles whose current buffer is B copy their central into A
__global__ void k_gather(const float* __restrict__ src,
                         float* __restrict__ dst,
                         const unsigned char* __restrict__ st) {
  int tix = blockIdx.x;
  if (!(st[tix] & 2)) return;  // already in A
  int by = tix >> 6, bx = tix & (NB - 1);
  int r = threadIdx.x >> 3, c4 = threadIdx.x & 7;
  int off = (by * OT + r) * WW + bx * OT + 4 * c4;
  *(float4*)(dst + off) = *(const float4*)(src + off);
}

__global__ __launch_bounds__(256) void k_fused(float* __restrict__ bufA,
                                               float* __restrict__ bufB,
                                               const float* __restrict__ good,
                                               const unsigned char* __restrict__ st_in,
                                               unsigned char* __restrict__ st_out,
                                               Keys kk) {
  __shared__ float xs[SD * SD];                // current x
  __shared__ float ts[SD * SD];                // jittered field (frontier only)
  __shared__ unsigned long long fm[SD];        // per-row flag mask (⊆ colw)
  __shared__ unsigned long long cm[SD];        // commit masks (crw-guarded)
  __shared__ unsigned int s_flr[2];            // flagrows bitmask (self-clean)
  __shared__ unsigned int s_crw[2];            // commitrows bitmask
  __shared__ unsigned int s_nzr[2];            // rows with any x > 0.05
  __shared__ const float* s_ptr[9];            // per-neighbor cur buffer
  __shared__ int s_skip, s_mystat, s_committed;

  const int tid = threadIdx.x;
  const int wv = tid >> 6, ln = tid & 63;      // wave id (0..3), lane (=col)
  const int bx = blockIdx.x, by = blockIdx.y;
  const int tix = by * NB + bx;
  const int r0b = by * OT, c0b = bx * OT;      // output origin
  const int r0g = r0b - HALO, c0g = c0b - HALO;  // staged origin
  const bool top = (by == 0), bot = (by == NB - 1);
  const bool lef = (bx == 0), rig = (bx == NB - 1);
  const bool edge = top || bot || lef || rig;

  // ---- neighbor status scan: activity + buffer pointers
  {
    bool act = false;
    if (tid < 9) {
      int dy = tid / 3 - 1, dx = tid % 3 - 1;
      int ny = by + dy, nx = bx + dx;
      unsigned char stv = 0;
      if (ny >= 0 && ny < NB && nx >= 0 && nx < NB) stv = st_in[ny * NB + nx];
      act = (stv & 1) != 0;
      s_ptr[tid] = (stv & 2) ? bufB : bufA;
      if (tid == 4) s_mystat = stv;
    }
    unsigned long long b = __ballot(act);      // meaningful in wave 0
    if (tid == 0) s_skip = (b == 0ULL);
    if (tid < 2) { s_flr[tid] = 0u; s_crw[tid] = 0u; s_nzr[tid] = 0u; }
    if (tid == 0) s_committed = 0;
    __syncthreads();
  }
  const int mycur = (s_mystat >> 1) & 1;
  if (s_skip) {  // whole 3x3 quiet: frozen, data stays where it is
    if (tid == 0) st_out[tix] = (unsigned char)(mycur << 1);
    return;
  }

  // ---- stage raw x from per-tile cur buffers (clamp == -inf pad for max);
  //      also build nz-row mask (any x > 0.05 in row)
  if (!edge) {
#pragma unroll
    for (int k = 0; k < 4; ++k) {
      int q = tid + 256 * k;                   // 1024 float4s
      int sr = q >> 4, c4 = q & 15;
      int gr = r0g + sr, gc = c0g + 4 * c4;
      const float* base = s_ptr[((gr >> 5) - (by - 1)) * 3 + ((gc >> 5) - (bx - 1))];
      float4 v = *(const float4*)(base + gr * WW + gc);
      ((float4*)xs)[q] = v;
      bool any = v.x > 0.05f || v.y > 0.05f || v.z > 0.05f || v.w > 0.05f;
      unsigned long long b = __ballot(any);    // 4 rows x 16 lanes per wave
      if (ln == 0) {
        int rr = 4 * wv + 16 * k;              // 4-aligned: no word straddle
        unsigned int mb = 0;
#pragma unroll
        for (int i = 0; i < 4; ++i)
          if ((b >> (16 * i)) & 0xFFFFULL) mb |= 1u << i;
        if (mb) atomicOr(&s_nzr[rr >> 5], mb << (rr & 31));
      }
    }
  } else {
    for (int k = 0; k < 16; ++k) {
      int idx = tid + 256 * k;                 // one row per wave per iter
      int sr = idx >> 6, sc = idx & 63;
      int gr = r0g + sr; gr = gr < 0 ? 0 : (gr > HH - 1 ? HH - 1 : gr);
      int gc = c0g + sc; gc = gc < 0 ? 0 : (gc > WW - 1 ? WW - 1 : gc);
      const float* base = s_ptr[((gr >> 5) - (by - 1)) * 3 + ((gc >> 5) - (bx - 1))];
      float xv = base[gr * WW + gc];
      xs[idx] = xv;
      unsigned long long b = __ballot(xv > 0.05f);
      if (ln == 0 && b) atomicOr(&s_nzr[sr >> 5], 1u << (sr & 31));
    }
  }
  if (tid < SD) fm[tid] = 0ULL;
  __syncthreads();

  int broke = 0;
  for (int s = 0; s < kk.K; ++s) {
    // exactly-updatable rect this step (local coords)
    const int rlo = top ? HALO : s + 1;
    const int rhi = bot ? HALO + OT - 1 : SD - 2 - s;
    const int clo = lef ? HALO : s + 1;
    const int chi = rig ? HALO + OT - 1 : SD - 2 - s;
    const unsigned long long colw = rmask(clo, chi);
    const unsigned long long rowsrect = rmask(rlo, rhi);
    const unsigned long long crw_prev =
        s_crw[0] | ((unsigned long long)s_crw[1] << 32);

    // ---- pass A: flag eval (nz-gated full eval at s=0; commit-driven after)
    if (s == 0) {
      unsigned long long nzr = s_nzr[0] | ((unsigned long long)s_nzr[1] << 32);
      unsigned long long arows = dil1(nzr) & rowsrect;
      int idx = 0;
      while (arows) {
        int r = __builtin_ctzll(arows); arows &= arows - 1;
        if (((idx++) & 3) != wv) continue;
        float a = xs[((r - 1) << 6) + ln];
        float b = xs[(r << 6) + ln];
        float c = xs[((r + 1) << 6) + ln];
        float vv = fmaxf(fmaxf(a, b), c);      // vertical max, own col
        float hl = __shfl(vv, ln - 1);         // junk at lane 0 (never valid)
        float hr = __shfl(vv, ln + 1);         // junk at lane 63 (never valid)
        float M = fmaxf(fmaxf(hl, vv), hr);
        bool flag = false;
        if ((colw >> ln) & 1ULL) {
          float xv = b;
          if (__fsub_rn(M, xv) > 0.05f) {      // pre-test: good<1 => ub <= M
            float g = good[(r0g + r) * WW + (c0g + ln)];
            if (__fsub_rn(__fmul_rn(M, g), xv) > 0.05f) flag = true;
          }
        }
        unsigned long long f = __ballot(flag) & colw;
        if (ln == 0) {
          fm[r] = f;
          if (f) atomicOr(&s_flr[r >> 5], 1u << (r & 31));
        }
      }
      // rows outside dil1(nzr): window max <= 0.05 => fl(M-x) <= 0.05, no flag
    } else {
      unsigned long long arows = dil1(crw_prev) & rowsrect;
      int idx = 0;
      while (arows) {
        int r = __builtin_ctzll(arows); arows &= arows - 1;
        if (((idx++) & 3) != wv) continue;
        unsigned long long cn = 0ULL;
        if ((crw_prev >> (r - 1)) & 1ULL) cn |= cm[r - 1];
        if ((crw_prev >> r) & 1ULL) cn |= cm[r];
        if ((crw_prev >> (r + 1)) & 1ULL) cn |= cm[r + 1];
        unsigned long long d = dil1(cn) & colw;
        if (!d) continue;
        float a = xs[((r - 1) << 6) + ln];
        float b = xs[(r << 6) + ln];
        float c = xs[((r + 1) << 6) + ln];
        float vv = fmaxf(fmaxf(a, b), c);
        float hl = __shfl(vv, ln - 1);
        float hr = __shfl(vv, ln + 1);
        float M = fmaxf(fmaxf(hl, vv), hr);
        bool flag = false;
        if ((d >> ln) & 1ULL) {
          float xv = b;
          if (__fsub_rn(M, xv) > 0.05f) {
            float g = good[(r0g + r) * WW + (c0g + ln)];
            if (__fsub_rn(__fmul_rn(M, g), xv) > 0.05f) flag = true;
          }
        }
        // FIX: mask by current colw -- out-of-rect bits can never commit and
        // colw only shrinks, so dropping them is final and side-effect free.
        unsigned long long f = ((fm[r] & ~d) | (__ballot(flag) & d)) & colw;
        if (ln == 0) {
          fm[r] = f;
          if (f) atomicOr(&s_flr[r >> 5], 1u << (r & 31));
          else   atomicAnd(&s_flr[r >> 5], ~(1u << (r & 31)));
        }
      }
    }
    __syncthreads();  // B1: fm/flagrows visible

    const unsigned long long flr =
        s_flr[0] | ((unsigned long long)s_flr[1] << 32);
    const unsigned long long flrR = flr & rowsrect;
    if (!flrR) { broke = 1; break; }  // frozen => forever

    // ---- jitter frontier (rows in dilate1(live flag rows)); clear commitrows
    if (tid < 2) s_crw[tid] = 0u;
    {
      unsigned long long jrows = dil1(flrR) & rmask(rlo - 1, rhi + 1);
      int idx = 0;
      while (jrows) {
        int r = __builtin_ctzll(jrows); jrows &= jrows - 1;
        if (((idx++) & 3) != wv) continue;
        unsigned long long fu = 0ULL;
        if (r - 1 >= rlo && r - 1 <= rhi) fu |= fm[r - 1];
        if (r     >= rlo && r     <= rhi) fu |= fm[r];
        if (r + 1 >= rlo && r + 1 <= rhi) fu |= fm[r + 1];
        fu &= colw;
        if (!fu) continue;
        unsigned long long need = dil1(fu);
        if ((need >> ln) & 1ULL) {
          float xv = xs[(r << 6) + ln];
          float tv = 0.0f;
          if (xv != 0.0f) {                    // t = 0*s1 == +0 exactly
            int gr = r0g + r;  gr = gr < 0 ? 0 : (gr > HH - 1 ? HH - 1 : gr);
            int gc = c0g + ln; gc = gc < 0 ? 0 : (gc > WW - 1 ? WW - 1 : gc);
            float u = uniform01(kk.a0[s], kk.a1[s], (uint32_t)(gr * WW + gc));
            float s1 = __fadd_rn((float)(1.0 - 1e-4), __fmul_rn(1e-4f, u));
            tv = __fmul_rn(xv, s1);
          }
          ts[(r << 6) + ln] = tv;
        }
      }
    }
    __syncthreads();  // B2: ts visible, crw cleared

    // ---- pass B: exact maxpool(t) + coin + commit at flagged px;
    //      self-clean flr rows whose current-rect flags are gone
    {
      unsigned long long brows = flrR;
      int idx = 0;
      while (brows) {
        int r = __builtin_ctzll(brows); brows &= brows - 1;
        if (((idx++) & 3) != wv) continue;
        unsigned long long wf = fm[r] & colw;
        if (!wf) {  // FIX: stale row (rect shrank past its flags) -> clean
          if (ln == 0) atomicAnd(&s_flr[r >> 5], ~(1u << (r & 31)));
          continue;
        }
        // ts garbage only exists >1 lane away from any flag, never consumed
        float t0 = ts[((r - 1) << 6) + ln];
        float t1 = ts[(r << 6) + ln];
        float t2 = ts[((r + 1) << 6) + ln];
        float vt = fmaxf(fmaxf(t0, t1), t2);
        float hl = __shfl(vt, ln - 1);
        float hr = __shfl(vt, ln + 1);
        float m = fmaxf(fmaxf(hl, vt), hr);
        bool ok = false;
        float v = 0.0f;
        if ((wf >> ln) & 1ULL) {
          int gp = (r0g + r) * WW + (c0g + ln);  // in rect => in bounds
          float xv = xs[(r << 6) + ln];
          v = __fmul_rn(m, good[gp]);
          if (__fsub_rn(v, xv) > 0.05f) {      // exact test -> coin draw
            float u2 = uniform01(kk.b0[s], kk.b1[s], (uint32_t)gp);
            ok = (u2 > 0.5f);
          }
        }
        unsigned long long bal = __ballot(ok);
        if (ok) xs[(r << 6) + ln] = v;         // max(v,x)=v since v-x>THR>0
        if (bal && ln == 0) {
          cm[r] = bal;
          atomicOr(&s_crw[r >> 5], 1u << (r & 31));
          s_committed = 1;
        }
      }
    }
    __syncthreads();  // B3: commits/crw/s_committed visible

    // ---- refresh dup ring for grid-edge tiles (only layer 15/48 is read)
    if (edge) {
      unsigned long long crw =
          s_crw[0] | ((unsigned long long)s_crw[1] << 32);
      if (crw) {  // no commits => xs unchanged => ring still valid
        if (top && tid < SD) xs[(15 << 6) + tid] = xs[(16 << 6) + tid];
        if (bot && tid < SD) xs[(48 << 6) + tid] = xs[(47 << 6) + tid];
        __syncthreads();
        if (lef && tid < SD) xs[(tid << 6) + 15] = xs[(tid << 6) + 16];
        if (rig && tid < SD) xs[(tid << 6) + 48] = xs[(tid << 6) + 47];
        __syncthreads();
      }
    }
  }

  // ---- writeback only if something changed; toggle cur bit accordingly
  int newcur = mycur;
  if (s_committed) {  // set before B3 of its step => visible (exits barrier'd)
    newcur = mycur ^ 1;
    float* dst = mycur ? bufA : bufB;          // write the OTHER buffer
    int r = tid >> 3, c4 = tid & 7;            // 32 rows x 8 float4
    *(float4*)(dst + (r0b + r) * WW + c0b + 4 * c4) =
        *(const float4*)(xs + ((r + HALO) << 6) + HALO + 4 * c4);
  }
  if (tid == 0)
    st_out[tix] = (unsigned char)((broke ? 0 : 1) | (newcur << 1));
}

extern "C" void kernel_launch(void* const* d_in, const int* in_sizes, int n_in,
                              void* d_out, int out_size, void* d_ws, size_t ws_size,
                              hipStream_t stream) {
  const float* seed = (const float*)d_in[0];
  const float* hab  = (const float*)d_in[1];
  const float* good = (const float*)d_in[2];
  float* bufA = (float*)d_out;
  float* bufB = (float*)d_ws;
  unsigned char* stA = (unsigned char*)d_ws + (16u << 20);  // after bufB
  unsigned char* stB = stA + NTILE;

  k_init<<<dim3(NPIX / 256), dim3(256), 0, stream>>>(seed, hab, good, bufB, stA);

  // sum(delta)==0.0 exactly (required for early exit) is unreachable once any
  // seed is nonzero (coin toss gives delta = -x < 0 somewhere) -> all 100 steps.
  unsigned char* stIn = stA; unsigned char* stOut = stB;
  dim3 grd(NB, NB), blk(256);
  for (int base = 0; base < 100; base += K_MAX) {
    Keys kk;
    kk.K = (100 - base < K_MAX) ? (100 - base) : K_MAX;
    for (int s = 0; s < kk.K; ++s) {
      uint32_t f0, f1;
      tf2x32(0u, 42u, 0u, (uint32_t)(base + s), &f0, &f1);  // fold_in(key, i)
      tf2x32(f0, f1, 0u, 0u, &kk.a0[s], &kk.a1[s]);         // split -> jitter
      tf2x32(f0, f1, 0u, 1u, &kk.b0[s], &kk.b1[s]);         // split -> coin
    }
    k_fused<<<grd, blk, 0, stream>>>(bufA, bufB, good, stIn, stOut, kk);
    unsigned char* t = stIn; stIn = stOut; stOut = t;
  }
  // consolidate: tiles whose final cur buffer is B -> copy central into d_out
  k_gather<<<dim3(NTILE), blk, 0, stream>>>(bufB, bufA, stIn);
}

// Round 11
// 1220.490 us; speedup vs baseline: 1.0631x; 1.0081x over previous
//
#include <hip/hip_runtime.h>
#include <stdint.h>

// RandomPropagate: 100 steps of jitter -> 3x3 maxpool -> coin mask -> goodness
// scale -> threshold commit, on a 2048x2048 f32 grid.
//
// Round 11 = Round 10 (flag hygiene, verified absmax 0.0) + cross-launch FLAG
// PERSISTENCE. R10 counters: FETCH ~30 MB on every launch => ~all tiles still
// stage; the 9-tile binary skip is too conservative and the s=0 full flag
// pass (all nz rows) runs everywhere each launch. Now:
//  - each tile saves its central 32x32 flag mask (32 u32) at launch end.
//    K=15 (<= HALO-1) keeps rect(final) >= central+1 ring, and a closing
//    commit-driven pass-A at s==K folds the last step's commits, so saved
//    central flags are EXACT flags of the final x.
//  - next launch: staged 64x64 flag window = 9 neighbors' saved masks
//    (192 u32 loads + shifts), masked to rect(0). No s=0 recompute.
//  - exact skip: window empty => no commit possible at s=0 => x frozen =>
//    flags frozen => frozen whole launch. Copy 32 fm words + status, return.
//    (no staging / good / RNG; stuck pixels pin <=4 tiles, not 9-hoods.)
//  - fm arrays ping-pong with statuses (dispatch order undefined => readers
//    see only last-launch snapshots).
// Launch 0: nzr-gated full eval (as R10) seeds the masks. 100 = 6x15 + 10.
// Values, flag algebra, and every consumed RNG bit identical to R10.
//
// PRNG: JAX threefry2x32, partitionable mode (bit-exact, absmax 0.0 R1-R10):
//   fold_in(key, i)       = tf2x32(key, (0, i))
//   split(F)[j]           = tf2x32(F,   (0, j))
//   random_bits32(key, p) = o0 ^ o1 of tf2x32(key, (0, p))
//   uniform01(bits)       = bitcast((bits>>9)|0x3f800000) - 1.0f
// All f32 math uses _rn intrinsics to forbid FMA contraction.

#define HH 2048
#define WW 2048
#define NPIX (HH * WW)
#define SD 64           // staged tile side (1 wave per row)
#define OT 32           // output tile side
#define HALO 16
#define K_STEP 15       // steps per launch (<= HALO-1 for exact saved flags)
#define K_MAX 16
#define NB (WW / OT)    // 64 tile-blocks per side
#define NTILE (NB * NB)

// ---------- threefry2x32, exact JAX round structure ----------
__host__ __device__ __forceinline__ void tf2x32(uint32_t k0, uint32_t k1,
                                                uint32_t c0, uint32_t c1,
                                                uint32_t* o0, uint32_t* o1) {
  uint32_t ks2 = k0 ^ k1 ^ 0x1BD11BDAu;
  uint32_t x0 = c0 + k0, x1 = c1 + k1;
#define TFR(r) do { x0 += x1; x1 = (x1 << (r)) | (x1 >> (32 - (r))); x1 ^= x0; } while (0);
  TFR(13) TFR(15) TFR(26) TFR(6)
  x0 += k1; x1 += ks2 + 1u;
  TFR(17) TFR(29) TFR(16) TFR(24)
  x0 += ks2; x1 += k0 + 2u;
  TFR(13) TFR(15) TFR(26) TFR(6)
  x0 += k0; x1 += k1 + 3u;
  TFR(17) TFR(29) TFR(16) TFR(24)
  x0 += k1; x1 += ks2 + 4u;
  TFR(13) TFR(15) TFR(26) TFR(6)
  x0 += ks2; x1 += k0 + 5u;
#undef TFR
  *o0 = x0; *o1 = x1;
}

__device__ __forceinline__ float uniform01(uint32_t ka, uint32_t kb, uint32_t p) {
  uint32_t o0, o1;
  tf2x32(ka, kb, 0u, p, &o0, &o1);
  uint32_t bits = o0 ^ o1;  // partitionable 32-bit XOR fold
  return __uint_as_float((bits >> 9) | 0x3F800000u) - 1.0f;
}

__device__ __forceinline__ unsigned long long dil1(unsigned long long m) {
  return m | (m << 1) | (m >> 1);
}
__device__ __forceinline__ unsigned long long rmask(int lo, int hi) {
  return (~0ULL >> (63 - (hi - lo))) << lo;  // bits lo..hi
}

struct Keys {
  uint32_t a0[K_MAX], a1[K_MAX], b0[K_MAX], b1[K_MAX];
  int K, first;
};

// x0 = seed*habitat*goodness (seed exactly 0/1 => rounding exact); arm
// statuses: cur = B for all tiles.
__global__ void k_init(const float* __restrict__ seed,
                       const float* __restrict__ hab,
                       const float* __restrict__ good,
                       float* __restrict__ x,
                       unsigned char* __restrict__ st) {
  int p = blockIdx.x * blockDim.x + threadIdx.x;
  if (p >= NPIX) return;
  x[p] = __fmul_rn(__fmul_rn(seed[p], hab[p]), good[p]);
  if (p < NTILE) st[p] = 1;  // cur = B
}

// consolidate: tiles whose current buffer is B copy their central into A
__global__ void k_gather(const float* __restrict__ src,
                         float* __restrict__ dst,
                         const unsigned char* __restrict__ st) {
  int tix = blockIdx.x;
  if (!(st[tix] & 1)) return;  // already in A
  int by = tix >> 6, bx = tix & (NB - 1);
  int r = threadIdx.x >> 3, c4 = threadIdx.x & 7;
  int off = (by * OT + r) * WW + bx * OT + 4 * c4;
  *(float4*)(dst + off) = *(const float4*)(src + off);
}

__global__ __launch_bounds__(256) void k_fused(float* __restrict__ bufA,
                                               float* __restrict__ bufB,
                                               const float* __restrict__ good,
                                               const unsigned char* __restrict__ st_in,
                                               unsigned char* __restrict__ st_out,
                                               const uint32_t* __restrict__ fm_in,
                                               uint32_t* __restrict__ fm_out,
                                               Keys kk) {
  __shared__ float xs[SD * SD];                // current x
  __shared__ float ts[SD * SD];                // jittered field (frontier only)
  __shared__ unsigned long long fm[SD];        // per-row flag mask
  __shared__ unsigned long long cm[SD];        // commit masks (crw-guarded)
  __shared__ unsigned int s_flr[2];            // flagrows bitmask (self-clean)
  __shared__ unsigned int s_crw[2];            // commitrows bitmask
  __shared__ unsigned int s_nzr[2];            // rows with any x > 0.05 (L0)
  __shared__ const float* s_ptr[9];            // per-neighbor cur buffer
  __shared__ int s_mystat, s_committed;

  const int tid = threadIdx.x;
  const int wv = tid >> 6, ln = tid & 63;      // wave id (0..3), lane (=col)
  const int bx = blockIdx.x, by = blockIdx.y;
  const int tix = by * NB + bx;
  const int r0b = by * OT, c0b = bx * OT;      // output origin
  const int r0g = r0b - HALO, c0g = c0b - HALO;  // staged origin
  const bool top = (by == 0), bot = (by == NB - 1);
  const bool lef = (bx == 0), rig = (bx == NB - 1);
  const bool edge = top || bot || lef || rig;

  if (tid < 2) { s_flr[tid] = 0u; s_crw[tid] = 0u; s_nzr[tid] = 0u; }
  if (tid == 0) s_committed = 0;
  __syncthreads();

  // ---- load persisted flag window (not launch 0); exact skip if empty
  if (!kk.first) {
    if (tid < SD) {
      int gr = r0g + tid;
      unsigned long long f = 0ULL;
      const int rlo0 = top ? HALO : 1, rhi0 = bot ? HALO + OT - 1 : SD - 2;
      if (gr >= 0 && gr < HH && tid >= rlo0 && tid <= rhi0) {
        int ty = gr >> 5, lr = gr & 31;
        uint32_t wL = 0, wM, wR = 0;
        if (bx > 0)      wL = fm_in[(ty * NB + bx - 1) * 32 + lr];
        wM = fm_in[(ty * NB + bx) * 32 + lr];
        if (bx < NB - 1) wR = fm_in[(ty * NB + bx + 1) * 32 + lr];
        f = ((unsigned long long)(wL >> 16)) |
            ((unsigned long long)wM << 16) |
            ((unsigned long long)(wR & 0xFFFFu) << 48);
        f &= rmask(lef ? HALO : 1, rig ? HALO + OT - 1 : SD - 2);  // colw(0)
      }
      fm[tid] = f;
      if (f) atomicOr(&s_flr[tid >> 5], 1u << (tid & 31));
    }
    __syncthreads();
    if ((s_flr[0] | s_flr[1]) == 0u) {
      // no flag anywhere in staged window => no commit at s=0 => x frozen =>
      // flags frozen => frozen for the whole launch. Nothing moves.
      if (tid < 32) fm_out[tix * 32 + tid] = fm_in[tix * 32 + tid];
      if (tid == 0) st_out[tix] = st_in[tix];
      return;
    }
  } else {
    if (tid < SD) fm[tid] = 0ULL;
  }

  // ---- neighbor status scan: buffer pointers
  if (tid < 9) {
    int dy = tid / 3 - 1, dx = tid % 3 - 1;
    int ny = by + dy, nx = bx + dx;
    unsigned char stv = 0;
    if (ny >= 0 && ny < NB && nx >= 0 && nx < NB) stv = st_in[ny * NB + nx];
    s_ptr[tid] = (stv & 1) ? bufB : bufA;
  }
  if (tid == 0) s_mystat = st_in[tix];
  __syncthreads();

  // ---- stage raw x from per-tile cur buffers (clamp == -inf pad for max);
  //      nz-row mask built only on launch 0 (seeds the flag eval)
  if (!edge) {
#pragma unroll
    for (int k = 0; k < 4; ++k) {
      int q = tid + 256 * k;                   // 1024 float4s
      int sr = q >> 4, c4 = q & 15;
      int gr = r0g + sr, gc = c0g + 4 * c4;
      const float* base = s_ptr[((gr >> 5) - (by - 1)) * 3 + ((gc >> 5) - (bx - 1))];
      float4 v = *(const float4*)(base + gr * WW + gc);
      ((float4*)xs)[q] = v;
      if (kk.first) {
        bool any = v.x > 0.05f || v.y > 0.05f || v.z > 0.05f || v.w > 0.05f;
        unsigned long long b = __ballot(any);  // 4 rows x 16 lanes per wave
        if (ln == 0) {
          int rr = 4 * wv + 16 * k;            // 4-aligned: no word straddle
          unsigned int mb = 0;
#pragma unroll
          for (int i = 0; i < 4; ++i)
            if ((b >> (16 * i)) & 0xFFFFULL) mb |= 1u << i;
          if (mb) atomicOr(&s_nzr[rr >> 5], mb << (rr & 31));
        }
      }
    }
  } else {
    for (int k = 0; k < 16; ++k) {
      int idx = tid + 256 * k;                 // one row per wave per iter
      int sr = idx >> 6, sc = idx & 63;
      int gr = r0g + sr; gr = gr < 0 ? 0 : (gr > HH - 1 ? HH - 1 : gr);
      int gc = c0g + sc; gc = gc < 0 ? 0 : (gc > WW - 1 ? WW - 1 : gc);
      const float* base = s_ptr[((gr >> 5) - (by - 1)) * 3 + ((gc >> 5) - (bx - 1))];
      float xv = base[gr * WW + gc];
      xs[idx] = xv;
      if (kk.first) {
        unsigned long long b = __ballot(xv > 0.05f);
        if (ln == 0 && b) atomicOr(&s_nzr[sr >> 5], 1u << (sr & 31));
      }
    }
  }
  __syncthreads();

  int broke = 0;
  // s == kk.K is a flags-only closing pass (folds last step's commits into fm
  // so the saved central masks are exact for the final x).
  for (int s = 0; s <= kk.K; ++s) {
    // exactly-updatable rect this step (local coords)
    const int rlo = top ? HALO : s + 1;
    const int rhi = bot ? HALO + OT - 1 : SD - 2 - s;
    const int clo = lef ? HALO : s + 1;
    const int chi = rig ? HALO + OT - 1 : SD - 2 - s;
    const unsigned long long colw = rmask(clo, chi);
    const unsigned long long rowsrect = rmask(rlo, rhi);
    const unsigned long long crw_prev =
        s_crw[0] | ((unsigned long long)s_crw[1] << 32);

    // ---- pass A: flag eval (launch0 full at s=0; commit-driven after;
    //      s=0 on later launches: flags preloaded, nothing to do)
    if (s == 0) {
      if (kk.first) {
        unsigned long long nzr = s_nzr[0] | ((unsigned long long)s_nzr[1] << 32);
        unsigned long long arows = dil1(nzr) & rowsrect;
        int idx = 0;
        while (arows) {
          int r = __builtin_ctzll(arows); arows &= arows - 1;
          if (((idx++) & 3) != wv) continue;
          float a = xs[((r - 1) << 6) + ln];
          float b = xs[(r << 6) + ln];
          float c = xs[((r + 1) << 6) + ln];
          float vv = fmaxf(fmaxf(a, b), c);    // vertical max, own col
          float hl = __shfl(vv, ln - 1);       // junk at lane 0 (never valid)
          float hr = __shfl(vv, ln + 1);       // junk at lane 63 (never valid)
          float M = fmaxf(fmaxf(hl, vv), hr);
          bool flag = false;
          if ((colw >> ln) & 1ULL) {
            float xv = b;
            if (__fsub_rn(M, xv) > 0.05f) {    // pre-test: good<1 => ub <= M
              float g = good[(r0g + r) * WW + (c0g + ln)];
              if (__fsub_rn(__fmul_rn(M, g), xv) > 0.05f) flag = true;
            }
          }
          unsigned long long f = __ballot(flag) & colw;
          if (ln == 0) {
            fm[r] = f;
            if (f) atomicOr(&s_flr[r >> 5], 1u << (r & 31));
          }
        }
        // rows outside dil1(nzr): window max <= 0.05 => no flag possible
      }
    } else {
      unsigned long long arows = dil1(crw_prev) & rowsrect;
      int idx = 0;
      while (arows) {
        int r = __builtin_ctzll(arows); arows &= arows - 1;
        if (((idx++) & 3) != wv) continue;
        unsigned long long cn = 0ULL;
        if ((crw_prev >> (r - 1)) & 1ULL) cn |= cm[r - 1];
        if ((crw_prev >> r) & 1ULL) cn |= cm[r];
        if ((crw_prev >> (r + 1)) & 1ULL) cn |= cm[r + 1];
        unsigned long long d = dil1(cn) & colw;
        if (!d) continue;
        float a = xs[((r - 1) << 6) + ln];
        float b = xs[(r << 6) + ln];
        float c = xs[((r + 1) << 6) + ln];
        float vv = fmaxf(fmaxf(a, b), c);
        float hl = __shfl(vv, ln - 1);
        float hr = __shfl(vv, ln + 1);
        float M = fmaxf(fmaxf(hl, vv), hr);
        bool flag = false;
        if ((d >> ln) & 1ULL) {
          float xv = b;
          if (__fsub_rn(M, xv) > 0.05f) {
            float g = good[(r0g + r) * WW + (c0g + ln)];
            if (__fsub_rn(__fmul_rn(M, g), xv) > 0.05f) flag = true;
          }
        }
        // mask by current colw: out-of-rect bits can never commit; colw only
        // shrinks, so dropping is final and side-effect free (R10 fix).
        unsigned long long f = ((fm[r] & ~d) | (__ballot(flag) & d)) & colw;
        if (ln == 0) {
          fm[r] = f;
          if (f) atomicOr(&s_flr[r >> 5], 1u << (r & 31));
          else   atomicAnd(&s_flr[r >> 5], ~(1u << (r & 31)));
        }
      }
    }
    __syncthreads();  // B1: fm/flagrows visible

    if (s == kk.K) break;  // closing pass done; fm final for save

    const unsigned long long flr =
        s_flr[0] | ((unsigned long long)s_flr[1] << 32);
    const unsigned long long flrR = flr & rowsrect;
    if (!flrR) { broke = 1; break; }  // frozen => forever

    // ---- jitter frontier (rows in dilate1(live flag rows)); clear commitrows
    if (tid < 2) s_crw[tid] = 0u;
    {
      unsigned long long jrows = dil1(flrR) & rmask(rlo - 1, rhi + 1);
      int idx = 0;
      while (jrows) {
        int r = __builtin_ctzll(jrows); jrows &= jrows - 1;
        if (((idx++) & 3) != wv) continue;
        unsigned long long fu = 0ULL;
        if (r - 1 >= rlo && r - 1 <= rhi) fu |= fm[r - 1];
        if (r     >= rlo && r     <= rhi) fu |= fm[r];
        if (r + 1 >= rlo && r + 1 <= rhi) fu |= fm[r + 1];
        fu &= colw;
        if (!fu) continue;
        unsigned long long need = dil1(fu);
        if ((need >> ln) & 1ULL) {
          float xv = xs[(r << 6) + ln];
          float tv = 0.0f;
          if (xv != 0.0f) {                    // t = 0*s1 == +0 exactly
            int gr = r0g + r;  gr = gr < 0 ? 0 : (gr > HH - 1 ? HH - 1 : gr);
            int gc = c0g + ln; gc = gc < 0 ? 0 : (gc > WW - 1 ? WW - 1 : gc);
            float u = uniform01(kk.a0[s], kk.a1[s], (uint32_t)(gr * WW + gc));
            float s1 = __fadd_rn((float)(1.0 - 1e-4), __fmul_rn(1e-4f, u));
            tv = __fmul_rn(xv, s1);
          }
          ts[(r << 6) + ln] = tv;
        }
      }
    }
    __syncthreads();  // B2: ts visible, crw cleared

    // ---- pass B: exact maxpool(t) + coin + commit at flagged px;
    //      self-clean flr rows whose current-rect flags are gone
    {
      unsigned long long brows = flrR;
      int idx = 0;
      while (brows) {
        int r = __builtin_ctzll(brows); brows &= brows - 1;
        if (((idx++) & 3) != wv) continue;
        unsigned long long wf = fm[r] & colw;
        if (!wf) {  // stale row (rect shrank past its flags) -> clean
          if (ln == 0) atomicAnd(&s_flr[r >> 5], ~(1u << (r & 31)));
          continue;
        }
        // ts garbage only exists >1 lane away from any flag, never consumed
        float t0 = ts[((r - 1) << 6) + ln];
        float t1 = ts[(r << 6) + ln];
        float t2 = ts[((r + 1) << 6) + ln];
        float vt = fmaxf(fmaxf(t0, t1), t2);
        float hl = __shfl(vt, ln - 1);
        float hr = __shfl(vt, ln + 1);
        float m = fmaxf(fmaxf(hl, vt), hr);
        bool ok = false;
        float v = 0.0f;
        if ((wf >> ln) & 1ULL) {
          int gp = (r0g + r) * WW + (c0g + ln);  // in rect => in bounds
          float xv = xs[(r << 6) + ln];
          v = __fmul_rn(m, good[gp]);
          if (__fsub_rn(v, xv) > 0.05f) {      // exact test -> coin draw
            float u2 = uniform01(kk.b0[s], kk.b1[s], (uint32_t)gp);
            ok = (u2 > 0.5f);
          }
        }
        unsigned long long bal = __ballot(ok);
        if (ok) xs[(r << 6) + ln] = v;         // max(v,x)=v since v-x>THR>0
        if (bal && ln == 0) {
          cm[r] = bal;
          atomicOr(&s_crw[r >> 5], 1u << (r & 31));
          s_committed = 1;
        }
      }
    }
    __syncthreads();  // B3: commits/crw/s_committed visible

    // ---- refresh dup ring for grid-edge tiles (only layer 15/48 is read)
    if (edge) {
      unsigned long long crw =
          s_crw[0] | ((unsigned long long)s_crw[1] << 32);
      if (crw) {  // no commits => xs unchanged => ring still valid
        if (top && tid < SD) xs[(15 << 6) + tid] = xs[(16 << 6) + tid];
        if (bot && tid < SD) xs[(48 << 6) + tid] = xs[(47 << 6) + tid];
        __syncthreads();
        if (lef && tid < SD) xs[(tid << 6) + 15] = xs[(tid << 6) + 16];
        if (rig && tid < SD) xs[(tid << 6) + 48] = xs[(tid << 6) + 47];
        __syncthreads();
      }
    }
  }

  // ---- save exact central flag mask (cols 16..47 of rows 16..47)
  if (tid < 32)
    fm_out[tix * 32 + tid] = (uint32_t)(fm[(16 + tid)] >> 16);

  // ---- writeback only if something changed; toggle cur bit accordingly
  const int mycur = s_mystat & 1;
  int newcur = mycur;
  if (s_committed) {  // set before a B3 barrier => visible (exits barrier'd)
    newcur = mycur ^ 1;
    float* dst = mycur ? bufA : bufB;          // write the OTHER buffer
    int r = tid >> 3, c4 = tid & 7;            // 32 rows x 8 float4
    *(float4*)(dst + (r0b + r) * WW + c0b + 4 * c4) =
        *(const float4*)(xs + ((r + HALO) << 6) + HALO + 4 * c4);
  }
  if (tid == 0) st_out[tix] = (unsigned char)newcur;
  (void)broke;
}

extern "C" void kernel_launch(void* const* d_in, const int* in_sizes, int n_in,
                              void* d_out, int out_size, void* d_ws, size_t ws_size,
                              hipStream_t stream) {
  const float* seed = (const float*)d_in[0];
  const float* hab  = (const float*)d_in[1];
  const float* good = (const float*)d_in[2];
  float* bufA = (float*)d_out;
  float* bufB = (float*)d_ws;
  unsigned char* stA = (unsigned char*)d_ws + (16u << 20);       // 4 KB
  unsigned char* stB = stA + NTILE;
  uint32_t* fmA = (uint32_t*)((char*)d_ws + (16u << 20) + (1u << 16));  // 512 KB
  uint32_t* fmB = fmA + NTILE * 32;

  k_init<<<dim3(NPIX / 256), dim3(256), 0, stream>>>(seed, hab, good, bufB, stA);

  // sum(delta)==0.0 exactly (required for early exit) is unreachable once any
  // seed is nonzero (coin toss gives delta = -x < 0 somewhere) -> all 100 steps.
  unsigned char* stIn = stA; unsigned char* stOut = stB;
  uint32_t* fmIn = fmA; uint32_t* fmOut = fmB;
  dim3 grd(NB, NB), blk(256);
  for (int base = 0; base < 100; base += K_STEP) {
    Keys kk;
    kk.K = (100 - base < K_STEP) ? (100 - base) : K_STEP;
    kk.first = (base == 0) ? 1 : 0;
    for (int s = 0; s < kk.K; ++s) {
      uint32_t f0, f1;
      tf2x32(0u, 42u, 0u, (uint32_t)(base + s), &f0, &f1);  // fold_in(key, i)
      tf2x32(f0, f1, 0u, 0u, &kk.a0[s], &kk.a1[s]);         // split -> jitter
      tf2x32(f0, f1, 0u, 1u, &kk.b0[s], &kk.b1[s]);         // split -> coin
    }
    k_fused<<<grd, blk, 0, stream>>>(bufA, bufB, good, stIn, stOut,
                                     fmIn, fmOut, kk);
    unsigned char* t = stIn; stIn = stOut; stOut = t;
    uint32_t* tf = fmIn; fmIn = fmOut; fmOut = tf;
  }
  // consolidate: tiles whose final cur buffer is B -> copy central into d_out
  k_gather<<<dim3(NTILE), blk, 0, stream>>>(bufB, bufA, stIn);
}